// Round 10
// baseline (142.246 us; speedup 1.0000x reference)
//
#include <hip/hip_runtime.h>

// Forbid FMA contraction EVERYWHERE: the fallback path recomputes distances
// and must be bit-identical to the main loop AND to numpy's unfused
// ((dx*dx + dy*dy) + dz*dz).
#pragma clang fp contract(off)

typedef unsigned long long u64;
typedef unsigned int u32;

#define BB 8
#define LL 2048
#define MM 4096
#define KK 25
#define WPB 16           // waves (queries) per block
#define TPB 1024
#define SENT 0xFFFFFFFFFFFFFFFFull

// Wave64 all-lanes min-reduce. xor1/xor2 via quad_perm DPP, xor4/xor8 via
// half-row/row mirrors (mirror pairing crosses the already-reduced halves, a
// valid reduction combiner), xor16 via ds_swizzle, xor32 via bpermute shfl.
static __device__ __forceinline__ u32 wave_min_u32(u32 x) {
    u32 t;
    t = (u32)__builtin_amdgcn_update_dpp(0, (int)x, 0xB1, 0xF, 0xF, true);  // quad_perm(1,0,3,2) = xor1
    x = t < x ? t : x;
    t = (u32)__builtin_amdgcn_update_dpp(0, (int)x, 0x4E, 0xF, 0xF, true);  // quad_perm(2,3,0,1) = xor2
    x = t < x ? t : x;
    t = (u32)__builtin_amdgcn_update_dpp(0, (int)x, 0x141, 0xF, 0xF, true); // row_half_mirror
    x = t < x ? t : x;
    t = (u32)__builtin_amdgcn_update_dpp(0, (int)x, 0x140, 0xF, 0xF, true); // row_mirror
    x = t < x ? t : x;
    t = (u32)__builtin_amdgcn_ds_swizzle((int)x, 0x401F);                   // xor16
    x = t < x ? t : x;
    t = (u32)__shfl_xor((int)x, 32, 64);                                    // xor32
    x = t < x ? t : x;
    return x;
}

// ROUND 10 = round-9 kernel (PASSED, 76.4us, absmax 0) with exactly ONE
// change: per-lane top-3 instead of top-4 (round-2 proved top-3 + rescan
// semantics correct). Saves 5 instr/j in the hot cascade; rescan rate rises
// ~3.5% -> ~4.8% per query (cheap, amortized).
__global__ void __launch_bounds__(TPB, 8) knn_kernel(
    const float* __restrict__ CB, const float* __restrict__ maskA,
    const float* __restrict__ Y, const int* __restrict__ Yt,
    const int* __restrict__ Ym, float* __restrict__ out)
{
    // {x, y, z, wmask} per candidate; wmask = 0.0f (valid) or 1000.0f (masked).
    __shared__ float4 sP[MM];   // 64 KiB -> 2 blocks/CU (wave-cap bound anyway)

    const int tid  = threadIdx.x;
    const int lane = tid & 63;
    const int wv   = tid >> 6;
    const int blk  = blockIdx.x;
    const int b    = blk >> 7;        // 128 blocks per batch (LL/WPB)
    const int qg   = blk & 127;

    // ---- stage Y[b] + Y_m into LDS ----
    const float* Yb  = Y  + (size_t)b * MM * 3;
    const int*   Ymb = Ym + (size_t)b * MM;
    for (int p = tid; p < MM; p += TPB) {
        float4 v;
        v.x = Yb[3 * p + 0];
        v.y = Yb[3 * p + 1];
        v.z = Yb[3 * p + 2];
        v.w = Ymb[p] ? 0.0f : 1000.0f;
        sP[p] = v;
    }
    __syncthreads();

    // ---- per-wave query ----
    const int l = qg * WPB + wv;
    const int q = b * LL + l;

    float* out_y = out;                                   // [B,L,K,3]
    float* out_t = out + (size_t)BB * LL * KK * 3;        // [B,L,K]
    float* out_m = out_t + (size_t)BB * LL * KK;          // [B,L,K]
    float* out_d = out_m + (size_t)BB * LL * KK;          // [B,L]

    // ---- fast path: query masked out => every value exactly 1000.0,
    // top_k ties resolve to indices 0..24 (verified rounds 2/4/5/8/9).
    if (maskA[q] == 0.0f) {
        if (lane < KK) {
            const int p = lane;
            float4 c = sP[p];
            const size_t o = (size_t)q * KK + lane;
            out_y[3 * o + 0] = c.x;
            out_y[3 * o + 1] = c.y;
            out_y[3 * o + 2] = c.z;
            out_t[o] = (float)Yt[(size_t)b * MM + p];
            out_m[o] = (c.w == 0.0f) ? 1.0f : 0.0f;
            if (lane == 0) out_d[q] = sqrtf(1000.0f);
        }
        return;
    }

    const float cx = CB[3 * q + 0];
    const float cy = CB[3 * q + 1];
    const float cz = CB[3 * q + 2];

    // Single source of truth for the masked distance — main pass + fallback;
    // contract(off) keeps it bit-exact vs numpy everywhere. Masked candidates
    // are exactly 1000.0f (required: for outlier queries the reference picks
    // masked 1000.0 entries BEFORE valid ones with dsq > 1000 — round-6/7
    // lesson).
    auto distv = [&](int j) -> float {
        float4 c = sP[(j << 6) | lane];
        float dx = cx - c.x;
        float dy = cy - c.y;
        float dz = cz - c.z;
        float dsq = (dx * dx + dy * dy) + dz * dz;
        return (c.w != 0.0f) ? c.w : dsq;
    };

    // ---- fused distance + per-lane stable top-3 (ascending by (v, j)) ----
    float v1 = 3.0e38f, v2 = 3.0e38f, v3 = 3.0e38f;
    int   j1 = 0, j2 = 0, j3 = 0;
#pragma unroll
    for (int j = 0; j < 64; ++j) {
        float v = distv(j);
        // stable cascade insert (strict < keeps earlier j ahead on ties);
        // c1 => c2 => c3 since v1<=v2<=v3
        bool c1 = v < v1, c2 = v < v2, c3 = v < v3;
        float nv3 = c3 ? (c2 ? v2 : v) : v3;  int nj3 = c3 ? (c2 ? j2 : j) : j3;
        float nv2 = c2 ? (c1 ? v1 : v) : v2;  int nj2 = c2 ? (c1 ? j1 : j) : j2;
        float nv1 = c1 ? v : v1;              int nj1 = c1 ? j : j1;
        v1 = nv1; v2 = nv2; v3 = nv3;
        j1 = nj1; j2 = nj2; j3 = nj3;
    }

    // keys: (value_bits + 1) << 32 | p — monotone in (value, index), unique.
    u64 k1 = ((u64)(__float_as_uint(v1) + 1u) << 32) | (u32)((j1 << 6) | lane);
    u64 k2 = ((u64)(__float_as_uint(v2) + 1u) << 32) | (u32)((j2 << 6) | lane);
    u64 k3 = ((u64)(__float_as_uint(v3) + 1u) << 32) | (u32)((j3 << 6) | lane);
    u64 lastpop = 0;                 // key of last element popped from THIS lane
    u64 mykey = 0;

    // ---- 25 extractions: DPP value min-reduce + ballot winner ----
#pragma unroll 1
    for (int it = 0; it < KK; ++it) {
        bool need = (k1 == SENT);
        if (__any(need)) {             // ~4.8%: a lane consumed its 3
            u64 found = SENT;
#pragma unroll 8
            for (int j = 0; j < 64; ++j) {
                float v = distv(j);
                u64 key = ((u64)(__float_as_uint(v) + 1u) << 32)
                        | (u32)((j << 6) | lane);
                if (key > lastpop && key < found) found = key;
            }
            if (need) k1 = found;
        }
        const u32 vh = (u32)(k1 >> 32);   // value bits (+1)
        const u32 vl = (u32)k1;           // global index p
        const u32 bv = wave_min_u32(vh);
        u64 ball = __ballot(vh == bv);
        u32 bp;
        if (__popcll(ball) == 1) {        // wave-uniform; ~always taken
            int wl = __ffsll((unsigned long long)ball) - 1;
            bp = (u32)__shfl((int)vl, wl, 64);
        } else {                          // exact value tie: min index wins
            u32 cp = (vh == bv) ? vl : 0xFFFFFFFFu;
#pragma unroll
            for (int off = 32; off; off >>= 1) {
                u32 o = __shfl_xor(cp, off, 64);
                cp = (o < cp) ? o : cp;
            }
            bp = cp;
        }
        if (lane == it) mykey = ((u64)bv << 32) | bp;
        if (vh == bv && vl == bp) {       // unique keys -> exactly one winner
            lastpop = k1;
            k1 = k2; k2 = k3; k3 = SENT;
        }
    }

    // ---- outputs (flat concat, all as float32) ----
    if (lane < KK) {
        const int p   = (int)(mykey & 0xFFFFFFFFull);
        const float v = __uint_as_float((u32)(mykey >> 32) - 1u);
        float4 c = sP[p];
        const size_t o = (size_t)q * KK + lane;
        out_y[3 * o + 0] = c.x;
        out_y[3 * o + 1] = c.y;
        out_y[3 * o + 2] = c.z;
        out_t[o] = (float)Yt[(size_t)b * MM + p];
        out_m[o] = (c.w == 0.0f) ? 1.0f : 0.0f;
        if (lane == 0) out_d[q] = sqrtf(v);
    }
}

extern "C" void kernel_launch(void* const* d_in, const int* in_sizes, int n_in,
                              void* d_out, int out_size, void* d_ws, size_t ws_size,
                              hipStream_t stream) {
    const float* CB   = (const float*)d_in[0];
    const float* mask = (const float*)d_in[1];
    const float* Y    = (const float*)d_in[2];
    const int*   Yt   = (const int*)d_in[3];
    const int*   Ym   = (const int*)d_in[4];
    float* out = (float*)d_out;

    dim3 grid(BB * LL / WPB);
    dim3 block(TPB);
    hipLaunchKernelGGL(knn_kernel, grid, block, 0, stream, CB, mask, Y, Yt, Ym, out);
}

// Round 11
// 127.710 us; speedup vs baseline: 1.1138x; 1.1138x over previous
//
#include <hip/hip_runtime.h>

// Forbid FMA contraction EVERYWHERE: the fallback path recomputes distances
// and must be bit-identical to the main loop AND to numpy's unfused
// ((dx*dx + dy*dy) + dz*dz).
#pragma clang fp contract(off)

typedef unsigned long long u64;
typedef unsigned int u32;

#define BB 8
#define LL 2048
#define MM 4096
#define KK 25
#define WPB 16           // waves (queries) per block
#define TPB 1024
#define SENT 0xFFFFFFFFFFFFFFFFull

// Wave64 min-reduce -> wave-uniform scalar. Levels 1-4: proven round-9 DPP
// (quad xor1/xor2, half-row mirror, row mirror) => every lane holds its
// 16-row's min. Then row_bcast15/row_bcast31 (classic GCN wave64 pattern)
// fold rows so lanes 48-63 hold the global min; readlane(63) broadcasts it.
// bcast steps pass old=x (identity for min) so invalid-source lanes are safe.
static __device__ __forceinline__ u32 wave_min_u32(u32 x) {
    u32 t;
    t = (u32)__builtin_amdgcn_update_dpp(0, (int)x, 0xB1, 0xF, 0xF, true);   // xor1
    x = t < x ? t : x;
    t = (u32)__builtin_amdgcn_update_dpp(0, (int)x, 0x4E, 0xF, 0xF, true);   // xor2
    x = t < x ? t : x;
    t = (u32)__builtin_amdgcn_update_dpp(0, (int)x, 0x141, 0xF, 0xF, true);  // half-row mirror
    x = t < x ? t : x;
    t = (u32)__builtin_amdgcn_update_dpp(0, (int)x, 0x140, 0xF, 0xF, true);  // row mirror
    x = t < x ? t : x;
    // rows folded: row1<-r0min, row2<-r1min, row3<-r2min
    t = (u32)__builtin_amdgcn_update_dpp((int)x, (int)x, 0x142, 0xF, 0xF, false); // row_bcast15
    x = t < x ? t : x;
    // lanes 32-63 <- lane31 (= min(r0,r1)); lanes 48-63 now hold global min
    t = (u32)__builtin_amdgcn_update_dpp((int)x, (int)x, 0x143, 0xF, 0xF, false); // row_bcast31
    x = t < x ? t : x;
    return (u32)__builtin_amdgcn_readlane((int)x, 63);
}

// ROUND 11 = round-9 kernel (best: PASSED, 76.4us, absmax 0; round-10's
// top-3 variant regressed and is reverted) with the extraction reduce/
// broadcast moved off the LDS pipe (DPP row_bcast + readlane).
__global__ void __launch_bounds__(TPB, 8) knn_kernel(
    const float* __restrict__ CB, const float* __restrict__ maskA,
    const float* __restrict__ Y, const int* __restrict__ Yt,
    const int* __restrict__ Ym, float* __restrict__ out)
{
    // {x, y, z, wmask} per candidate; wmask = 0.0f (valid) or 1000.0f (masked).
    __shared__ float4 sP[MM];   // 64 KiB -> 2 blocks/CU (wave-cap bound anyway)

    const int tid  = threadIdx.x;
    const int lane = tid & 63;
    const int wv   = tid >> 6;
    const int blk  = blockIdx.x;
    const int b    = blk >> 7;        // 128 blocks per batch (LL/WPB)
    const int qg   = blk & 127;

    // ---- stage Y[b] + Y_m into LDS ----
    const float* Yb  = Y  + (size_t)b * MM * 3;
    const int*   Ymb = Ym + (size_t)b * MM;
    for (int p = tid; p < MM; p += TPB) {
        float4 v;
        v.x = Yb[3 * p + 0];
        v.y = Yb[3 * p + 1];
        v.z = Yb[3 * p + 2];
        v.w = Ymb[p] ? 0.0f : 1000.0f;
        sP[p] = v;
    }
    __syncthreads();

    // ---- per-wave query ----
    const int l = qg * WPB + wv;
    const int q = b * LL + l;

    float* out_y = out;                                   // [B,L,K,3]
    float* out_t = out + (size_t)BB * LL * KK * 3;        // [B,L,K]
    float* out_m = out_t + (size_t)BB * LL * KK;          // [B,L,K]
    float* out_d = out_m + (size_t)BB * LL * KK;          // [B,L]

    // ---- fast path: query masked out => every value exactly 1000.0,
    // top_k ties resolve to indices 0..24 (verified rounds 2/4/5/8/9).
    if (maskA[q] == 0.0f) {
        if (lane < KK) {
            const int p = lane;
            float4 c = sP[p];
            const size_t o = (size_t)q * KK + lane;
            out_y[3 * o + 0] = c.x;
            out_y[3 * o + 1] = c.y;
            out_y[3 * o + 2] = c.z;
            out_t[o] = (float)Yt[(size_t)b * MM + p];
            out_m[o] = (c.w == 0.0f) ? 1.0f : 0.0f;
            if (lane == 0) out_d[q] = sqrtf(1000.0f);
        }
        return;
    }

    const float cx = CB[3 * q + 0];
    const float cy = CB[3 * q + 1];
    const float cz = CB[3 * q + 2];

    // Single source of truth for the masked distance — main pass + fallback;
    // contract(off) keeps it bit-exact vs numpy everywhere. Masked candidates
    // are exactly 1000.0f (required: for outlier queries the reference ranks
    // masked 1000.0 entries before valid ones with dsq > 1000).
    auto distv = [&](int j) -> float {
        float4 c = sP[(j << 6) | lane];
        float dx = cx - c.x;
        float dy = cy - c.y;
        float dz = cz - c.z;
        float dsq = (dx * dx + dy * dy) + dz * dz;
        return (c.w != 0.0f) ? c.w : dsq;
    };

    // ---- fused distance + per-lane stable top-4 (ascending by (v, j)) ----
    float v1 = 3.0e38f, v2 = 3.0e38f, v3 = 3.0e38f, v4 = 3.0e38f;
    int   j1 = 0, j2 = 0, j3 = 0, j4 = 0;
#pragma unroll
    for (int j = 0; j < 64; ++j) {
        float v = distv(j);
        // stable cascade insert (strict < keeps earlier j ahead on ties);
        // c1 => c2 => c3 => c4 since v1<=v2<=v3<=v4
        bool c1 = v < v1, c2 = v < v2, c3 = v < v3, c4 = v < v4;
        float nv4 = c4 ? (c3 ? v3 : v) : v4;  int nj4 = c4 ? (c3 ? j3 : j) : j4;
        float nv3 = c3 ? (c2 ? v2 : v) : v3;  int nj3 = c3 ? (c2 ? j2 : j) : j3;
        float nv2 = c2 ? (c1 ? v1 : v) : v2;  int nj2 = c2 ? (c1 ? j1 : j) : j2;
        float nv1 = c1 ? v : v1;              int nj1 = c1 ? j : j1;
        v1 = nv1; v2 = nv2; v3 = nv3; v4 = nv4;
        j1 = nj1; j2 = nj2; j3 = nj3; j4 = nj4;
    }

    // keys: (value_bits + 1) << 32 | p — monotone in (value, index), unique.
    u64 k1 = ((u64)(__float_as_uint(v1) + 1u) << 32) | (u32)((j1 << 6) | lane);
    u64 k2 = ((u64)(__float_as_uint(v2) + 1u) << 32) | (u32)((j2 << 6) | lane);
    u64 k3 = ((u64)(__float_as_uint(v3) + 1u) << 32) | (u32)((j3 << 6) | lane);
    u64 k4 = ((u64)(__float_as_uint(v4) + 1u) << 32) | (u32)((j4 << 6) | lane);
    u64 lastpop = 0;                 // key of last element popped from THIS lane
    u64 mykey = 0;

    // ---- 25 extractions: DPP value min-reduce + ballot winner ----
#pragma unroll 1
    for (int it = 0; it < KK; ++it) {
        bool need = (k1 == SENT);
        if (__any(need)) {             // rare (~3.5%): a lane consumed its 4
            u64 found = SENT;
#pragma unroll 8
            for (int j = 0; j < 64; ++j) {
                float v = distv(j);
                u64 key = ((u64)(__float_as_uint(v) + 1u) << 32)
                        | (u32)((j << 6) | lane);
                if (key > lastpop && key < found) found = key;
            }
            if (need) k1 = found;
        }
        const u32 vh = (u32)(k1 >> 32);   // value bits (+1)
        const u32 vl = (u32)k1;           // global index p
        const u32 bv = wave_min_u32(vh);  // wave-uniform global min value
        u64 ball = __ballot(vh == bv);    // wave-uniform mask
        u32 bp;
        if (__popcll(ball) == 1) {        // wave-uniform; ~always taken
            int wl = __ffsll((unsigned long long)ball) - 1;
            bp = (u32)__builtin_amdgcn_readlane((int)vl, wl);  // scalar bcast
        } else {                          // exact value tie: min index wins
            u32 cp = (vh == bv) ? vl : 0xFFFFFFFFu;
#pragma unroll
            for (int off = 32; off; off >>= 1) {
                u32 o = __shfl_xor(cp, off, 64);
                cp = (o < cp) ? o : cp;
            }
            bp = cp;
        }
        if (lane == it) mykey = ((u64)bv << 32) | bp;
        if (vh == bv && vl == bp) {       // unique keys -> exactly one winner
            lastpop = k1;
            k1 = k2; k2 = k3; k3 = k4; k4 = SENT;
        }
    }

    // ---- outputs (flat concat, all as float32) ----
    if (lane < KK) {
        const int p   = (int)(mykey & 0xFFFFFFFFull);
        const float v = __uint_as_float((u32)(mykey >> 32) - 1u);
        float4 c = sP[p];
        const size_t o = (size_t)q * KK + lane;
        out_y[3 * o + 0] = c.x;
        out_y[3 * o + 1] = c.y;
        out_y[3 * o + 2] = c.z;
        out_t[o] = (float)Yt[(size_t)b * MM + p];
        out_m[o] = (c.w == 0.0f) ? 1.0f : 0.0f;
        if (lane == 0) out_d[q] = sqrtf(v);
    }
}

extern "C" void kernel_launch(void* const* d_in, const int* in_sizes, int n_in,
                              void* d_out, int out_size, void* d_ws, size_t ws_size,
                              hipStream_t stream) {
    const float* CB   = (const float*)d_in[0];
    const float* mask = (const float*)d_in[1];
    const float* Y    = (const float*)d_in[2];
    const int*   Yt   = (const int*)d_in[3];
    const int*   Ym   = (const int*)d_in[4];
    float* out = (float*)d_out;

    dim3 grid(BB * LL / WPB);
    dim3 block(TPB);
    hipLaunchKernelGGL(knn_kernel, grid, block, 0, stream, CB, mask, Y, Yt, Ym, out);
}